// Round 6
// baseline (1424.255 us; speedup 1.0000x reference)
//
#include <hip/hip_runtime.h>
#include <math.h>

#define BS 8192
#define SL 49
#define FDIM 11
#define ROWS (BS*SL)

typedef __attribute__((ext_vector_type(8))) short bf16x8;
typedef __attribute__((ext_vector_type(4))) float f32x4;

__device__ __forceinline__ unsigned short f2bf(float f) {
  unsigned u = __float_as_uint(f);
  u += 0x7FFFu + ((u >> 16) & 1u);
  return (unsigned short)(u >> 16);
}
__device__ __forceinline__ float bf2f(unsigned short h) {
  return __uint_as_float(((unsigned)h) << 16);
}
__device__ __forceinline__ float tanhshrink_f(float x) {
  float e = __expf(2.f * x);
  return (x - 1.f) + __fdividef(2.f, e + 1.f);
}

// ---------------- BN stats ----------------
__global__ __launch_bounds__(256) void k_stats(const float* __restrict__ inp,
                                               double* __restrict__ gsum) {
  const int nblk = gridDim.x;
  const int per = (ROWS + nblk - 1) / nblk;
  const int r0 = blockIdx.x * per;
  int r1 = r0 + per; if (r1 > ROWS) r1 = ROWS;
  float s[9], q[9];
#pragma unroll
  for (int j = 0; j < 9; ++j) { s[j] = 0.f; q[j] = 0.f; }
  for (int r = r0 + threadIdx.x; r < r1; r += 256) {
    const float* row = inp + r * FDIM;
#pragma unroll
    for (int j = 0; j < 9; ++j) {
      float v = row[j < 8 ? j : 10];
      s[j] += v; q[j] += v * v;
    }
  }
#pragma unroll
  for (int j = 0; j < 9; ++j) {
    for (int off = 32; off; off >>= 1) {
      s[j] += __shfl_down(s[j], off);
      q[j] += __shfl_down(q[j], off);
    }
  }
  __shared__ float red[4][18];
  const int wid = threadIdx.x >> 6;
  const int lane = threadIdx.x & 63;
  if (lane == 0) {
#pragma unroll
    for (int j = 0; j < 9; ++j) { red[wid][j] = s[j]; red[wid][9 + j] = q[j]; }
  }
  __syncthreads();
  if (threadIdx.x < 18) {
    float t = red[0][threadIdx.x] + red[1][threadIdx.x] +
              red[2][threadIdx.x] + red[3][threadIdx.x];
    atomicAdd(&gsum[threadIdx.x], (double)t);
  }
}

// ---------------- finalize BN + layer-0 q ----------------
__global__ __launch_bounds__(256) void k_finalize(const double* __restrict__ gsum,
                           const float* __restrict__ gamma,
                           const float* __restrict__ beta,
                           const float* __restrict__ hidden,
                           const float* __restrict__ Wq,
                           float* __restrict__ bnp,
                           float* __restrict__ q0g) {
  int tid = threadIdx.x;
  if (tid < 9) {
    const double N = (double)ROWS;
    double mean = gsum[tid] / N;
    double msq  = gsum[9 + tid] / N;
    float var = (float)(msq - mean * mean);
    float sc = gamma[tid] / sqrtf(var + 1e-5f);
    bnp[tid] = sc;
    bnp[9 + tid] = beta[tid] - (float)mean * sc;
  }
  int s = tid >> 7, i2 = (tid >> 6) & 1, c = tid & 63;
  const float* W = Wq + (s << 12);
#pragma unroll
  for (int ii = 0; ii < 2; ++ii) {
    int i = i2 + 2 * ii;
    float a = 0.f;
    for (int k = 0; k < 64; ++k) a += hidden[i * 64 + k] * W[k * 64 + c];
    q0g[s * 256 + i * 64 + c] = a;
  }
}

// ---------------- pre-convert weights: transposed split-bf16 ----------------
// layout in wb: [xwTh 4096][xwTl 4096][ywTh 4096][ywTl 4096][wkTh 4*4096][wkTl 4*4096]
__global__ __launch_bounds__(256) void k_prep(const float* __restrict__ xe_w2,
                                              const float* __restrict__ ye_w2,
                                              const float* __restrict__ Wk,
                                              unsigned short* __restrict__ wb) {
  int idx = blockIdx.x * 256 + threadIdx.x;   // 0 .. 24575
  int mat = idx >> 12;
  int e = idx & 4095;
  int n = e >> 6, k = e & 63;                 // out[n*64+k] = W[k*64+n]
  float v; unsigned short *dh, *dl;
  if (mat == 0)      { v = xe_w2[k * 64 + n]; dh = wb;          dl = wb + 4096;  }
  else if (mat == 1) { v = ye_w2[k * 64 + n]; dh = wb + 8192;   dl = wb + 12288; }
  else { int m = mat - 2; v = Wk[(m << 12) + k * 64 + n];
         dh = wb + 16384 + (m << 12); dl = wb + 32768 + (m << 12); }
  unsigned short h = f2bf(v);
  dh[e] = h;
  dl[e] = f2bf(v - bf2f(h));
}

// ---------------- mega kernel: one block per (batch, stream) ----------------
// LDS ~54KB -> 3 blocks/CU.
__global__ __launch_bounds__(256, 3) void k_mega(
    const float* __restrict__ inp, const float* __restrict__ dists,
    const float* __restrict__ bnp, const float* __restrict__ q0g,
    const unsigned short* __restrict__ wb,
    const float* __restrict__ xe_w1, const float* __restrict__ xe_b1,
    const float* __restrict__ xe_w2, const float* __restrict__ xe_b2,
    const float* __restrict__ ye_w1, const float* __restrict__ ye_b1,
    const float* __restrict__ ye_b2,
    const float* __restrict__ learnable_y, const float* __restrict__ hidden_tokens,
    const float* __restrict__ Wq,
    const float* __restrict__ Wv, const float* __restrict__ Wo,
    const float* __restrict__ Wq2, const float* __restrict__ Wk2,
    const float* __restrict__ Wv2, const float* __restrict__ Wo2,
    float* __restrict__ enc)
{
  // KBf: first raw[49][12]+h1q[64]+bnl[18] (early), later K/T [48][68]
  __shared__ __align__(16) float KBf[48 * 68];
  // AstBuf: h1 split-bf16 [48][72] hi + [48][72] lo; later fp32 scratch (scb/qb/db/...)
  __shared__ __align__(16) unsigned short AstBuf[2 * 48 * 72];
  __shared__ __align__(16) float embf[48 * 64];        // ctx fp32 (a@ctx)
  __shared__ __align__(16) unsigned short EMBh[48 * 64]; // ctx bf16 hi (swizzled)
  __shared__ __align__(16) unsigned short EMBl[48 * 64]; // ctx bf16 lo (swizzled)
  __shared__ __align__(16) float cs8[49][8];
  __shared__ __align__(16) float Hs[4 * 64];

  float* rawp = KBf;            // [49][12]
  float* h1q  = KBf + 588;      // [64]
  float* bnlp = KBf + 652;      // [18]
  unsigned short* Asth = AstBuf;
  unsigned short* Astl = AstBuf + 48 * 72;
  float* fbuf = (float*)AstBuf; // valid after emb2 phase
  float* scb  = fbuf;           // [32][52]
  float* qbf  = fbuf + 1664;    // [4][64]
  float* dbp  = fbuf + 1920;    // [48]
  float* embq = fbuf + 1968;    // [64]
  float* q2   = fbuf + 2032;    // [64]
  float* o1   = fbuf + 2096;    // [64]
  float* a2   = fbuf + 2160;    // [32]

  const int tid  = threadIdx.x;
  const int lane = tid & 63;
  const int grp  = tid >> 6;
  const int l15  = lane & 15;
  const int quad = lane >> 4;
  const int b    = blockIdx.x >> 1;
  const int s    = blockIdx.x & 1;
  const float scale = 0.35355339059327373f;  // 1/sqrt(8)

  // ---- load input rows, bn params
  for (int i = tid; i < 49 * FDIM; i += 256) rawp[(i / FDIM) * 12 + (i % FDIM)] = inp[b * (49 * FDIM) + i];
  if (tid < 18) bnlp[tid] = bnp[tid];
  __syncthreads();

  // ---- rope trig from RAW 8,9 ; BN features {0..7,10}
  if (tid < 49) {
    float x = rawp[tid * 12 + 8], y = rawp[tid * 12 + 9];
    cs8[tid][0] = cosf(10.f * x); cs8[tid][1] = cosf(10.f * y);
    cs8[tid][2] = cosf(x);        cs8[tid][3] = cosf(y);
    cs8[tid][4] = sinf(10.f * x); cs8[tid][5] = sinf(10.f * y);
    cs8[tid][6] = sinf(x);        cs8[tid][7] = sinf(y);
  }
  for (int i = tid; i < 441; i += 256) {
    int t = i / 9, j = i - t * 9;
    int f = (j < 8) ? j : 10;
    rawp[t * 12 + f] = rawp[t * 12 + f] * bnlp[j] + bnlp[9 + j];
  }
  __syncthreads();

  if (s == 0 && tid < 10) enc[b * 138 + 128 + tid] = rawp[48 * 12 + tid];

  // ---- embed layer 1 -> Ast (split bf16), row 48 -> h1q (s==0)
  if (s == 0) {
    const float bias1 = xe_b1[lane];
    float acc[12];
    float acc12 = bias1;
#pragma unroll
    for (int j = 0; j < 12; ++j) acc[j] = bias1;
#pragma unroll
    for (int k = 0; k < 8; ++k) {
      float w = xe_w1[k * 64 + lane];
#pragma unroll
      for (int j = 0; j < 12; ++j) acc[j] += rawp[(grp + 4 * j) * 12 + k] * w;
      acc12 += rawp[48 * 12 + k] * w;
    }
#pragma unroll
    for (int j = 0; j < 12; ++j) {
      int t = grp + 4 * j;
      float a = tanhshrink_f(acc[j]);
      unsigned short h = f2bf(a);
      Asth[t * 72 + lane] = h;
      Astl[t * 72 + lane] = f2bf(a - bf2f(h));
    }
    if (grp == 0) h1q[lane] = tanhshrink_f(acc12);
  } else {
    const float w1y = ye_w1[lane];
    const float b1y = ye_b1[lane];
#pragma unroll
    for (int j = 0; j < 12; ++j) {
      int t = grp + 4 * j;
      float a = tanhshrink_f(rawp[t * 12 + 10] * w1y + b1y);
      unsigned short h = f2bf(a);
      Asth[t * 72 + lane] = h;
      Astl[t * 72 + lane] = f2bf(a - bf2f(h));
    }
  }
  __syncthreads();

  // ---- embed layer 2 via MFMA: emb(48x64) = h1(48x64) @ W2(64x64) + b2
  {
    const unsigned short* BTh = s ? (wb + 8192)  : wb;
    const unsigned short* BTl = s ? (wb + 12288) : (wb + 4096);
    const float* b2p = s ? ye_b2 : xe_b2;
#pragma unroll 1
    for (int i = 0; i < 3; ++i) {
      int T = grp + 4 * i;        // 0..11
      int rt = T % 3, ct = T / 3;
      int arow = rt * 16 + l15;
      int bcol = ct * 16 + l15;
      f32x4 acc = {0.f, 0.f, 0.f, 0.f};
#pragma unroll
      for (int ks = 0; ks < 2; ++ks) {
        int ko = ks * 32 + quad * 8;
        bf16x8 Ah = *(bf16x8*)&Asth[arow * 72 + ko];
        bf16x8 Al = *(bf16x8*)&Astl[arow * 72 + ko];
        bf16x8 Bh = *(const bf16x8*)(BTh + bcol * 64 + ko);
        bf16x8 Bl = *(const bf16x8*)(BTl + bcol * 64 + ko);
        acc = __builtin_amdgcn_mfma_f32_16x16x32_bf16(Ah, Bh, acc, 0, 0, 0);
        acc = __builtin_amdgcn_mfma_f32_16x16x32_bf16(Al, Bh, acc, 0, 0, 0);
        acc = __builtin_amdgcn_mfma_f32_16x16x32_bf16(Ah, Bl, acc, 0, 0, 0);
      }
      float bias = b2p[bcol];
#pragma unroll
      for (int r = 0; r < 4; ++r) {
        int t = rt * 16 + quad * 4 + r;
        float v = acc[r] + bias;
        embf[t * 64 + bcol] = v;
        int sw = (t & 3) << 4;
        unsigned short h = f2bf(v);
        EMBh[t * 64 + (bcol ^ sw)] = h;
        EMBl[t * 64 + (bcol ^ sw)] = f2bf(v - bf2f(h));
      }
    }
  }
  // row 48 (query row) in VALU while MFMA runs
  float r48 = 0.f;
  if (s == 0 && tid < 64) {
    r48 = xe_b2[lane];
    for (int k = 0; k < 64; ++k) r48 += h1q[k] * xe_w2[k * 64 + lane];
  }
  __syncthreads();   // emb done; Ast region becomes fbuf scratch

  if (tid < 64) embq[lane] = (s == 0) ? r48 : learnable_y[lane];
  if (tid >= 64 && tid < 112) dbp[tid - 64] = dists[b * 49 + (tid - 64)];
  Hs[grp * 64 + lane] = hidden_tokens[grp * 64 + lane];
  __syncthreads();

  // ---- 2 self-attention layers
#pragma unroll 1
  for (int l = 0; l < 2; ++l) {
    const float* Wv_p = Wv + ((l * 2 + s) << 12);
    const float* Wo_p = Wo + ((l * 2 + s) << 12);
    // q
    if (l == 0) {
      qbf[tid] = q0g[s * 256 + tid];
    } else {
      const float* Wq_p = Wq + ((2 + s) << 12);
      float a = 0.f;
      for (int k = 0; k < 64; k += 4) {
        float4 hv = *(float4*)&Hs[grp * 64 + k];
        a += hv.x * Wq_p[(k + 0) * 64 + lane] + hv.y * Wq_p[(k + 1) * 64 + lane]
           + hv.z * Wq_p[(k + 2) * 64 + lane] + hv.w * Wq_p[(k + 3) * 64 + lane];
      }
      qbf[tid] = a;
    }
    // K^T = WkT @ ctx^T via MFMA, rope in C-layout, scatter to KBf[t][c]
    {
      const unsigned short* ATh = wb + 16384 + ((l * 2 + s) << 12);
      const unsigned short* ATl = wb + 32768 + ((l * 2 + s) << 12);
      const int arow = grp * 16 + l15;   // output channel
      bf16x8 Ah0 = *(const bf16x8*)(ATh + arow * 64 + quad * 8);
      bf16x8 Ah1 = *(const bf16x8*)(ATh + arow * 64 + 32 + quad * 8);
      bf16x8 Al0 = *(const bf16x8*)(ATl + arow * 64 + quad * 8);
      bf16x8 Al1 = *(const bf16x8*)(ATl + arow * 64 + 32 + quad * 8);
      const int p0 = (quad * 2) & 3, p1 = (quad * 2 + 1) & 3;
      const int c0 = grp * 16 + quad * 4;
#pragma unroll 1
      for (int nt = 0; nt < 3; ++nt) {
        const int tcol = nt * 16 + l15;  // token
        const int sw = (tcol & 3) << 4;
        int k0 = (quad * 8) ^ sw;
        int k1 = (32 + quad * 8) ^ sw;
        bf16x8 Bh0 = *(bf16x8*)&EMBh[tcol * 64 + k0];
        bf16x8 Bl0 = *(bf16x8*)&EMBl[tcol * 64 + k0];
        bf16x8 Bh1 = *(bf16x8*)&EMBh[tcol * 64 + k1];
        bf16x8 Bl1 = *(bf16x8*)&EMBl[tcol * 64 + k1];
        f32x4 acc = {0.f, 0.f, 0.f, 0.f};
        acc = __builtin_amdgcn_mfma_f32_16x16x32_bf16(Ah0, Bh0, acc, 0, 0, 0);
        acc = __builtin_amdgcn_mfma_f32_16x16x32_bf16(Al0, Bh0, acc, 0, 0, 0);
        acc = __builtin_amdgcn_mfma_f32_16x16x32_bf16(Ah0, Bl0, acc, 0, 0, 0);
        acc = __builtin_amdgcn_mfma_f32_16x16x32_bf16(Ah1, Bh1, acc, 0, 0, 0);
        acc = __builtin_amdgcn_mfma_f32_16x16x32_bf16(Al1, Bh1, acc, 0, 0, 0);
        acc = __builtin_amdgcn_mfma_f32_16x16x32_bf16(Ah1, Bl1, acc, 0, 0, 0);
        float co0 = cs8[tcol][p0], si0 = cs8[tcol][4 + p0];
        float co1 = cs8[tcol][p1], si1 = cs8[tcol][4 + p1];
        KBf[tcol * 68 + c0 + 0] = co0 * acc[0] - si0 * acc[1];
        KBf[tcol * 68 + c0 + 1] = si0 * acc[0] + co0 * acc[1];
        KBf[tcol * 68 + c0 + 2] = co1 * acc[2] - si1 * acc[3];
        KBf[tcol * 68 + c0 + 3] = si1 * acc[2] + co1 * acc[3];
      }
    }
    __syncthreads();
    // scores + softmax fused (registers only)
    {
      const int t0 = tid & 7;
      const int i  = (tid >> 3) & 3;
      const int h  = tid >> 5;
      const int r  = tid >> 3;
      float4 qa = *(float4*)&qbf[i * 64 + h * 8];
      float4 qc = *(float4*)&qbf[i * 64 + h * 8 + 4];
      float v[6];
#pragma unroll
      for (int j = 0; j < 6; ++j) {
        int t = t0 + 8 * j;
        float4 ka = *(float4*)&KBf[t * 68 + h * 8];
        float4 kc = *(float4*)&KBf[t * 68 + h * 8 + 4];
        float a = qa.x * ka.x + qa.y * ka.y + qa.z * ka.z + qa.w * ka.w
                + qc.x * kc.x + qc.y * kc.y + qc.z * kc.z + qc.w * kc.w;
        v[j] = a * scale - dbp[t];
      }
      float m = fmaxf(fmaxf(fmaxf(v[0], v[1]), fmaxf(v[2], v[3])), fmaxf(v[4], v[5]));
      m = fmaxf(m, __shfl_xor(m, 1));
      m = fmaxf(m, __shfl_xor(m, 2));
      m = fmaxf(m, __shfl_xor(m, 4));
      float sum = 0.f;
#pragma unroll
      for (int j = 0; j < 6; ++j) { v[j] = __expf(v[j] - m); sum += v[j]; }
      sum += __shfl_xor(sum, 1);
      sum += __shfl_xor(sum, 2);
      sum += __shfl_xor(sum, 4);
      float inv = 1.f / sum;
#pragma unroll
      for (int j = 0; j < 6; ++j) scb[r * 52 + t0 + 8 * j] = v[j] * inv;
    }
    __syncthreads();
    // T = a @ ctx  (32 x 64) -> KBf rows 0..31
    {
      float acc[8];
#pragma unroll
      for (int m = 0; m < 8; ++m) acc[m] = 0.f;
      for (int tt = 0; tt < 48; tt += 4) {
        float e0 = embf[(tt + 0) * 64 + lane], e1 = embf[(tt + 1) * 64 + lane];
        float e2 = embf[(tt + 2) * 64 + lane], e3 = embf[(tt + 3) * 64 + lane];
#pragma unroll
        for (int m = 0; m < 8; ++m) {
          float4 sc4 = *(float4*)&scb[(grp + 4 * m) * 52 + tt];
          acc[m] += sc4.x * e0 + sc4.y * e1 + sc4.z * e2 + sc4.w * e3;
        }
      }
#pragma unroll
      for (int m = 0; m < 8; ++m) KBf[(grp + 4 * m) * 68 + lane] = acc[m];
    }
    __syncthreads();
    // out[i][lane] = sum_c T[h*4+i][c] * Wv[c][lane] -> qbf
    {
      const int r = ((lane >> 3) << 2) + grp;
      float a = 0.f;
      for (int c = 0; c < 64; c += 4) {
        float4 tv = *(float4*)&KBf[r * 68 + c];
        a += tv.x * Wv_p[(c + 0) * 64 + lane] + tv.y * Wv_p[(c + 1) * 64 + lane]
           + tv.z * Wv_p[(c + 2) * 64 + lane] + tv.w * Wv_p[(c + 3) * 64 + lane];
      }
      qbf[tid] = a;
    }
    __syncthreads();
    // H += out @ Wo
    {
      float a = Hs[grp * 64 + lane];
      for (int k = 0; k < 64; k += 4) {
        float4 av = *(float4*)&qbf[grp * 64 + k];
        a += av.x * Wo_p[(k + 0) * 64 + lane] + av.y * Wo_p[(k + 1) * 64 + lane]
           + av.z * Wo_p[(k + 2) * 64 + lane] + av.w * Wo_p[(k + 3) * 64 + lane];
      }
      Hs[grp * 64 + lane] = a;
    }
    __syncthreads();
  }

  // ---- final cross attention
  const float* Wq2_p = Wq2 + (s << 12);
  const float* Wk2_p = Wk2 + (s << 12);
  const float* Wv2_p = Wv2 + (s << 12);
  const float* Wo2_p = Wo2 + (s << 12);
  if (tid < 64) {
    float a = 0.f;
    for (int k = 0; k < 64; k += 4) {
      float4 cv = *(float4*)&embq[k];
      a += cv.x * Wq2_p[(k + 0) * 64 + lane] + cv.y * Wq2_p[(k + 1) * 64 + lane]
         + cv.z * Wq2_p[(k + 2) * 64 + lane] + cv.w * Wq2_p[(k + 3) * 64 + lane];
    }
    float other = __shfl_xor(a, 1);
    int p = (lane >> 1) & 3;
    float co = cs8[48][p], si = cs8[48][4 + p];
    q2[lane] = (lane & 1) ? (si * other + co * a) : (co * a - si * other);
  }
  {
    float aK = 0.f, aV = 0.f;
    for (int k = 0; k < 64; k += 4) {
      float4 hv = *(float4*)&Hs[grp * 64 + k];
      aK += hv.x * Wk2_p[(k + 0) * 64 + lane] + hv.y * Wk2_p[(k + 1) * 64 + lane]
          + hv.z * Wk2_p[(k + 2) * 64 + lane] + hv.w * Wk2_p[(k + 3) * 64 + lane];
      aV += hv.x * Wv2_p[(k + 0) * 64 + lane] + hv.y * Wv2_p[(k + 1) * 64 + lane]
          + hv.z * Wv2_p[(k + 2) * 64 + lane] + hv.w * Wv2_p[(k + 3) * 64 + lane];
    }
    KBf[grp * 68 + lane] = aK;        // k2 rows 0..3
    KBf[(8 + grp) * 68 + lane] = aV;  // v2 rows 8..11
  }
  __syncthreads();
  if (tid < 32) {
    int h = tid >> 2, i = tid & 3;
    float a = 0.f;
#pragma unroll
    for (int d = 0; d < 8; ++d) a += q2[h * 8 + d] * KBf[i * 68 + h * 8 + d];
    a *= scale;
    float m = fmaxf(a, __shfl_xor(a, 1));
    m = fmaxf(m, __shfl_xor(m, 2));
    float e = __expf(a - m);
    float sum = e + __shfl_xor(e, 1);
    sum += __shfl_xor(sum, 2);
    a2[tid] = e / sum;
  }
  __syncthreads();
  if (tid < 64) {
    int h = lane >> 3;
    float a = 0.f;
#pragma unroll
    for (int i = 0; i < 4; ++i) a += a2[h * 4 + i] * KBf[(8 + i) * 68 + lane];
    o1[lane] = a;
  }
  __syncthreads();
  if (tid < 64) {
    float a = 0.f;
    for (int k = 0; k < 64; k += 4) {
      float4 ov = *(float4*)&o1[k];
      a += ov.x * Wo2_p[(k + 0) * 64 + lane] + ov.y * Wo2_p[(k + 1) * 64 + lane]
         + ov.z * Wo2_p[(k + 2) * 64 + lane] + ov.w * Wo2_p[(k + 3) * 64 + lane];
    }
    enc[b * 138 + s * 64 + lane] = a;
  }
}

// ---------------- decoder ----------------
__global__ __launch_bounds__(256) void k_dec(
    const float* __restrict__ enc,
    const float* __restrict__ w0, const float* __restrict__ b0,
    const float* __restrict__ w1, const float* __restrict__ b1,
    const float* __restrict__ w2, const float* __restrict__ b2,
    float* __restrict__ out)
{
  __shared__ float encs[16][140];
  __shared__ float h0s[16][512];
  __shared__ float h1s[16][256];
  const int tid = threadIdx.x;
  const int rb = blockIdx.x * 16;

  for (int i = tid; i < 16 * 138; i += 256) {
    int r = i / 138, k = i - r * 138;
    encs[r][k] = enc[(rb + r) * 138 + k];
  }
  __syncthreads();
  {
    float acc0[16], acc1[16];
    const float bb0 = b0[tid], bb1 = b0[tid + 256];
#pragma unroll
    for (int r = 0; r < 16; ++r) { acc0[r] = bb0; acc1[r] = bb1; }
    for (int k = 0; k < 136; k += 4) {
      float wa0 = w0[(k + 0) * 512 + tid], wa1 = w0[(k + 1) * 512 + tid];
      float wa2 = w0[(k + 2) * 512 + tid], wa3 = w0[(k + 3) * 512 + tid];
      float wb0 = w0[(k + 0) * 512 + tid + 256], wb1 = w0[(k + 1) * 512 + tid + 256];
      float wb2 = w0[(k + 2) * 512 + tid + 256], wb3 = w0[(k + 3) * 512 + tid + 256];
#pragma unroll
      for (int r = 0; r < 16; ++r) {
        float4 ev = *(const float4*)&encs[r][k];
        acc0[r] += ev.x * wa0 + ev.y * wa1 + ev.z * wa2 + ev.w * wa3;
        acc1[r] += ev.x * wb0 + ev.y * wb1 + ev.z * wb2 + ev.w * wb3;
      }
    }
    for (int k = 136; k < 138; ++k) {
      float wa = w0[k * 512 + tid], wbv = w0[k * 512 + tid + 256];
#pragma unroll
      for (int r = 0; r < 16; ++r) {
        float e = encs[r][k];
        acc0[r] += e * wa; acc1[r] += e * wbv;
      }
    }
#pragma unroll
    for (int r = 0; r < 16; ++r) {
      float a = acc0[r]; h0s[r][tid] = a - tanhf(a);
      a = acc1[r];       h0s[r][tid + 256] = a - tanhf(a);
    }
  }
  __syncthreads();
  {
    float acc[16];
    const float bb = b1[tid];
#pragma unroll
    for (int r = 0; r < 16; ++r) acc[r] = bb;
    for (int k = 0; k < 512; k += 4) {
      float ww0 = w1[(k + 0) * 256 + tid], ww1 = w1[(k + 1) * 256 + tid];
      float ww2 = w1[(k + 2) * 256 + tid], ww3 = w1[(k + 3) * 256 + tid];
#pragma unroll
      for (int r = 0; r < 16; ++r) {
        float4 hv = *(const float4*)&h0s[r][k];
        acc[r] += hv.x * ww0 + hv.y * ww1 + hv.z * ww2 + hv.w * ww3;
      }
    }
#pragma unroll
    for (int r = 0; r < 16; ++r) { float a = acc[r]; h1s[r][tid] = a - tanhf(a); }
  }
  __syncthreads();
  {
    int r = tid >> 4, l16 = tid & 15;
    float a = 0.f;
    for (int kk = 0; kk < 16; ++kk) {
      int k = l16 + 16 * kk;
      a += h1s[r][k] * w2[k];
    }
    for (int off = 8; off; off >>= 1) a += __shfl_down(a, off, 16);
    if (l16 == 0) out[rb + r] = a + b2[0];
  }
}

extern "C" void kernel_launch(void* const* d_in, const int* in_sizes, int n_in,
                              void* d_out, int out_size, void* d_ws, size_t ws_size,
                              hipStream_t stream) {
  const float* inp        = (const float*)d_in[0];
  const float* dists      = (const float*)d_in[1];
  const float* bn_gamma   = (const float*)d_in[3];
  const float* bn_beta    = (const float*)d_in[4];
  const float* xe_w1      = (const float*)d_in[5];
  const float* xe_b1      = (const float*)d_in[6];
  const float* xe_w2      = (const float*)d_in[7];
  const float* xe_b2      = (const float*)d_in[8];
  const float* ye_w1      = (const float*)d_in[9];
  const float* ye_b1      = (const float*)d_in[10];
  const float* ye_w2      = (const float*)d_in[11];
  const float* ye_b2      = (const float*)d_in[12];
  const float* learnable  = (const float*)d_in[13];
  const float* hidden     = (const float*)d_in[14];
  const float* Wq         = (const float*)d_in[15];
  const float* Wk         = (const float*)d_in[16];
  const float* Wv         = (const float*)d_in[17];
  const float* Wo         = (const float*)d_in[18];
  const float* Wq2        = (const float*)d_in[19];
  const float* Wk2        = (const float*)d_in[20];
  const float* Wv2        = (const float*)d_in[21];
  const float* Wo2        = (const float*)d_in[22];
  const float* dec_w0     = (const float*)d_in[23];
  const float* dec_b0     = (const float*)d_in[24];
  const float* dec_w1     = (const float*)d_in[25];
  const float* dec_b1     = (const float*)d_in[26];
  const float* dec_w2     = (const float*)d_in[27];
  const float* dec_b2     = (const float*)d_in[28];

  double* gsum = (double*)d_ws;                              // 18 doubles
  float*  bnp  = (float*)((char*)d_ws + 256);                // 18 floats
  float*  q0g  = (float*)((char*)d_ws + 512);                // 512 floats
  float*  enc  = (float*)((char*)d_ws + 2560);               // 8192*138 floats
  unsigned short* wbuf = (unsigned short*)((char*)d_ws + 4524544); // 49152 ushorts

  hipMemsetAsync(d_ws, 0, 256, stream);
  k_stats   <<<512, 256, 0, stream>>>(inp, gsum);
  k_finalize<<<1, 256, 0, stream>>>(gsum, bn_gamma, bn_beta, hidden, Wq, bnp, q0g);
  k_prep    <<<96, 256, 0, stream>>>(xe_w2, ye_w2, Wk, wbuf);
  k_mega    <<<BS * 2, 256, 0, stream>>>(inp, dists, bnp, q0g, wbuf,
                                         xe_w1, xe_b1, xe_w2, xe_b2,
                                         ye_w1, ye_b1, ye_b2,
                                         learnable, hidden,
                                         Wq, Wv, Wo, Wq2, Wk2, Wv2, Wo2, enc);
  k_dec     <<<BS / 16, 256, 0, stream>>>(enc, dec_w0, dec_b0, dec_w1, dec_b1,
                                          dec_w2, dec_b2, (float*)d_out);
}